// Round 7
// baseline (182.651 us; speedup 1.0000x reference)
//
#include <hip/hip_runtime.h>
#include <hip/hip_bf16.h>
#include <cstddef>
#include <cstdint>

#define HID 1024
#define NHEADS 16
#define HDIM 64
#define BATCH 2
#define SEQ 2048
#define MROWS (BATCH * SEQ)   // 4096
#define BHT (BATCH * NHEADS)  // 32

typedef __attribute__((ext_vector_type(8))) short s8v;   // 8 x bf16 (4 VGPR)
typedef __attribute__((ext_vector_type(4))) float f4v;   // MFMA C/D frag
typedef __attribute__((ext_vector_type(2))) unsigned int u2v;

__device__ __forceinline__ unsigned int pkbf(float a, float b) {
    __hip_bfloat162 h = __float22bfloat162_rn(float2{a, b});  // x -> low 16
    union { __hip_bfloat162 v; unsigned int u; } c; c.v = h; return c.u;
}

__device__ __forceinline__ void lds_load16(void* lds, const void* g) {
    __builtin_amdgcn_global_load_lds(
        (const __attribute__((address_space(1))) void*)g,
        (__attribute__((address_space(3))) void*)lds, 16, 0, 0);
}

// ---------------- Stage 0: fused conversions + bf16 mask --------------------
__global__ __launch_bounds__(256) void conv_fused_kernel(
    const float* __restrict__ hs, const float* __restrict__ mask,
    const float* __restrict__ Wq, const float* __restrict__ Wk,
    const float* __restrict__ Wv,
    unsigned short* __restrict__ Ah, unsigned short* __restrict__ WTh,
    unsigned short* __restrict__ maskbf)
{
    if (blockIdx.x < 2048) {
        const int idx = (blockIdx.x * 256 + threadIdx.x) * 8;
        float4 v0 = *(const float4*)&hs[idx];
        float4 v1 = *(const float4*)&hs[idx + 4];
        union { unsigned int w[4]; } pk;
        pk.w[0] = pkbf(v0.x, v0.y);
        pk.w[1] = pkbf(v0.z, v0.w);
        pk.w[2] = pkbf(v1.x, v1.y);
        pk.w[3] = pkbf(v1.z, v1.w);
        *(uint4*)&Ah[idx] = *(uint4*)&pk;
    } else if (blockIdx.x < 2816) {
        const int bid = blockIdx.x - 2048;
        const int z = bid >> 8;
        const int rem = bid & 255;
        const float* W = (z == 0) ? Wq : (z == 1) ? Wk : Wv;
        unsigned short* th = WTh + (size_t)z * HID * HID;

        __shared__ float tile[64][65];
        const int t = threadIdx.x;
        const int kb = (rem >> 4) * 64, nb = (rem & 15) * 64;
        const int c4 = (t & 15) * 4;
        const int r0 = t >> 4;

#pragma unroll
        for (int i = 0; i < 4; ++i) {
            int r = r0 + i * 16;
            float4 v = *(const float4*)&W[(size_t)(kb + r) * HID + nb + c4];
            tile[r][c4 + 0] = v.x; tile[r][c4 + 1] = v.y;
            tile[r][c4 + 2] = v.z; tile[r][c4 + 3] = v.w;
        }
        __syncthreads();
#pragma unroll
        for (int i = 0; i < 4; ++i) {
            int n = r0 + i * 16;
            union { unsigned int w[2]; unsigned long long q; } pk;
            pk.w[0] = pkbf(tile[c4 + 0][n], tile[c4 + 1][n]);
            pk.w[1] = pkbf(tile[c4 + 2][n], tile[c4 + 3][n]);
            *(unsigned long long*)&th[(size_t)(nb + n) * HID + kb + c4] = pk.q;
        }
    } else {
        // bf16 copy of the {0,1} attention mask (B-fragment for the rowsum MFMA)
        const int idx = (blockIdx.x - 2816) * 256 + threadIdx.x;
        union { unsigned int u; unsigned short s[2]; } cv;
        cv.u = pkbf(mask[idx], 0.f);
        maskbf[idx] = cv.s[0];
    }
}

// ---------------- Stage 1: unified QKV GEMM, 2-phase pipelined --------------
// yb<8: Q (swapped MFMA, scale+bias); yb<16: K; else V (bias, x mask -> VTg).
#define QSCALE 0.18033688011112042f   // 0.125 * log2(e)

__global__ __launch_bounds__(256, 2) void qkv_mfma_kernel(
    const unsigned short* __restrict__ Ah, const unsigned short* __restrict__ WTh,
    const float* __restrict__ bq, const float* __restrict__ bk,
    const float* __restrict__ bv, const float* __restrict__ mask,
    unsigned short* __restrict__ Qg, unsigned short* __restrict__ Khi,
    unsigned short* __restrict__ VTg)
{
    __shared__ unsigned short S[32768];   // 64 KB: 2 bufs x (A 16KB + B 16KB)

    const int t = threadIdx.x;
    const int wave = t >> 6, lane = t & 63, quad = lane >> 4, l15 = lane & 15;
    const int sw = l15 & 7;
    const int wm = wave >> 1, wn = wave & 1;
    const int rowBase = blockIdx.x * 128;
    const int yb = blockIdx.y;             // 0..23
    const int colBase = yb * 128;          // row in stacked [3072][1024] WTh

    const int srow8 = lane >> 3;
    const int sc    = lane & 7;
    size_t goffA[4], goffB[4];
#pragma unroll
    for (int it = 0; it < 4; ++it) {
        const int row = (wave * 4 + it) * 8 + srow8;
        const int gx = (sc ^ (row & 7)) * 8;
        goffA[it] = (size_t)(rowBase + row) * HID + gx;
        goffB[it] = (size_t)(colBase + row) * HID + gx;
    }

    f4v acc[4][4];
#pragma unroll
    for (int mf = 0; mf < 4; ++mf)
#pragma unroll
        for (int nf = 0; nf < 4; ++nf) acc[mf][nf] = (f4v){0.f, 0.f, 0.f, 0.f};

    // prologue: stage K-step 0 into buffer 0
#pragma unroll
    for (int it = 0; it < 4; ++it) {
        lds_load16(&S[(wave * 4 + it) * 512], &Ah[goffA[it]]);
        lds_load16(&S[8192 + (wave * 4 + it) * 512], &WTh[goffB[it]]);
    }
    __syncthreads();

    const bool isQK = (yb < 16);           // block-uniform

    for (int kt = 0; kt < HID / 64; ++kt) {
        const int cur = (kt & 1) << 14;    // 0 / 16384 (u16 elems)
        const int nxt = cur ^ 16384;
        if (kt < HID / 64 - 1) {
            const int k0 = (kt + 1) * 64;
#pragma unroll
            for (int it = 0; it < 4; ++it) {
                lds_load16(&S[nxt + (wave * 4 + it) * 512], &Ah[goffA[it] + k0]);
                lds_load16(&S[nxt + 8192 + (wave * 4 + it) * 512], &WTh[goffB[it] + k0]);
            }
        }
        const unsigned short* AS = &S[cur];
        const unsigned short* BS = &S[cur + 8192];
#pragma unroll
        for (int kk = 0; kk < 2; ++kk) {
            const int csw = ((kk * 4 + quad) ^ sw) * 8;
            s8v af[4], bf[4];
#pragma unroll
            for (int mf = 0; mf < 4; ++mf)
                af[mf] = *(const s8v*)&AS[(wm * 64 + mf * 16 + l15) * 64 + csw];
#pragma unroll
            for (int nf = 0; nf < 4; ++nf)
                bf[nf] = *(const s8v*)&BS[(wn * 64 + nf * 16 + l15) * 64 + csw];
            if (isQK) {
#pragma unroll
                for (int mf = 0; mf < 4; ++mf)
#pragma unroll
                    for (int nf = 0; nf < 4; ++nf)
                        acc[mf][nf] = __builtin_amdgcn_mfma_f32_16x16x32_bf16(bf[nf], af[mf], acc[mf][nf], 0, 0, 0);
            } else {
#pragma unroll
                for (int mf = 0; mf < 4; ++mf)
#pragma unroll
                    for (int nf = 0; nf < 4; ++nf)
                        acc[mf][nf] = __builtin_amdgcn_mfma_f32_16x16x32_bf16(af[mf], bf[nf], acc[mf][nf], 0, 0, 0);
            }
        }
        __syncthreads();
    }

    if (yb < 8) {
        // Q epilogue (swapped layout: acc[mf][nf][r] = C[s][n], n = .. + quad*4 + r)
#pragma unroll
        for (int nf = 0; nf < 4; ++nf) {
            const int n0 = colBase + wn * 64 + nf * 16 + quad * 4;
            const float4 bb = *(const float4*)&bq[n0];
            const int h = n0 >> 6, d0 = n0 & 63;
#pragma unroll
            for (int mf = 0; mf < 4; ++mf) {
                const int rw = rowBase + wm * 64 + mf * 16 + l15;
                const int b = rw >> 11;
                const int ss = rw & (SEQ - 1);
                union { unsigned int w[2]; unsigned long long q; } pk;
                pk.w[0] = pkbf((acc[mf][nf][0] + bb.x) * QSCALE, (acc[mf][nf][1] + bb.y) * QSCALE);
                pk.w[1] = pkbf((acc[mf][nf][2] + bb.z) * QSCALE, (acc[mf][nf][3] + bb.w) * QSCALE);
                *(unsigned long long*)&Qg[((size_t)(b * NHEADS + h) * SEQ + ss) * HDIM + d0] = pk.q;
            }
        }
    } else if (yb < 16) {
        // K epilogue
#pragma unroll
        for (int nf = 0; nf < 4; ++nf) {
            const int nk = colBase - 1024 + wn * 64 + nf * 16 + quad * 4;
            const float4 bb = *(const float4*)&bk[nk];
            const int h = nk >> 6, d0 = nk & 63;
#pragma unroll
            for (int mf = 0; mf < 4; ++mf) {
                const int rw = rowBase + wm * 64 + mf * 16 + l15;
                const int b = rw >> 11;
                const int ss = rw & (SEQ - 1);
                union { unsigned int w[2]; unsigned long long q; } pk;
                pk.w[0] = pkbf(acc[mf][nf][0] + bb.x, acc[mf][nf][1] + bb.y);
                pk.w[1] = pkbf(acc[mf][nf][2] + bb.z, acc[mf][nf][3] + bb.w);
                *(unsigned long long*)&Khi[((size_t)(b * NHEADS + h) * SEQ + ss) * HDIM + d0] = pk.q;
            }
        }
    } else {
        // V epilogue (natural layout), pre-multiplied by the attention mask:
        // o = sum_k p_k * (m_k V_k) makes the QK-side mask add unnecessary.
#pragma unroll
        for (int nf = 0; nf < 4; ++nf) {
            const int nv = colBase - 2048 + wn * 64 + nf * 16 + l15;
            const float bb = bv[nv];
            const int h = nv >> 6, d = nv & 63;
#pragma unroll
            for (int mf = 0; mf < 4; ++mf) {
                const int rw0 = rowBase + wm * 64 + mf * 16 + quad * 4;
                const int b = rw0 >> 11;
                const int s0 = rw0 & (SEQ - 1);
                const float4 mv = *(const float4*)&mask[b * SEQ + s0];
                union { unsigned int w[2]; unsigned long long q; } pk;
                pk.w[0] = pkbf((acc[mf][nf][0] + bb) * mv.x, (acc[mf][nf][1] + bb) * mv.y);
                pk.w[1] = pkbf((acc[mf][nf][2] + bb) * mv.z, (acc[mf][nf][3] + bb) * mv.w);
                *(unsigned long long*)&VTg[((size_t)(b * NHEADS + h) * HDIM + d) * SEQ + s0] = pk.q;
            }
        }
    }
}

// ---------------- Stage 2: flash attention, qf=4 (64 q-rows/wave) -----------
// 256 q-rows/block, grid 32x8 = 256 blocks (1/CU, 1 wave/SIMD). The same 16
// ds_read_b128/wave/iter now feed 72 MFMAs (was 36): per-CU LDS duty halves.
// sacc starts at ZERO (no mask loads at the head of the chain); mask enters
// at the tail: V is pre-masked in qkv, rowsum l uses a bf16-mask B-fragment.
#define BC 64
#define NT (SEQ / BC)   // 32

__global__ __launch_bounds__(256, 1) void attn_mfma_kernel(
    const unsigned short* __restrict__ Qg, const unsigned short* __restrict__ Khi,
    const unsigned short* __restrict__ VTg,
    const unsigned short* __restrict__ maskbf, float* __restrict__ out)
{
    __shared__ unsigned short Kb[2][BC * HDIM];    // 2 x 8 KB, swizzled
    __shared__ unsigned short Vb[2][BC * HDIM];    // 2 x 8 KB, swizzled (V^T)

    const int t = threadIdx.x;
    const int wave = t >> 6, lane = t & 63, quad = lane >> 4, l15 = lane & 15;
    const int sw = l15 & 7;
    const int bh = blockIdx.x, b = bh >> 4, h = bh & (NHEADS - 1);
    const int qbase = blockIdx.y * 256 + wave * 64;

    const size_t hb = (size_t)bh * SEQ * HDIM;
    const unsigned short* kbase = Khi + hb;
    const unsigned short* vbase = VTg + hb;
    const unsigned short* mrow = maskbf + b * SEQ;

    s8v qh[4][2];
#pragma unroll
    for (int qf = 0; qf < 4; ++qf)
#pragma unroll
        for (int ds = 0; ds < 2; ++ds) {
            size_t off = hb + (size_t)(qbase + qf * 16 + l15) * HDIM + ds * 32 + quad * 8;
            qh[qf][ds] = *(const s8v*)&Qg[off];
        }

    f4v oacc[4][4], lacc[4];
#pragma unroll
    for (int qf = 0; qf < 4; ++qf) {
#pragma unroll
        for (int nf = 0; nf < 4; ++nf) oacc[qf][nf] = (f4v){0.f, 0.f, 0.f, 0.f};
        lacc[qf] = (f4v){0.f, 0.f, 0.f, 0.f};
    }

    // staging: 4 waves x 2 slices cover each 64x64 tile
    const int srow8 = lane >> 3;
    const int sc    = lane & 7;
    int koff[2], voff[2];
#pragma unroll
    for (int it = 0; it < 2; ++it) {
        const int row = (wave * 2 + it) * 8 + srow8;
        const int gx = (sc ^ (row & 7)) * 8;
        koff[it] = row * HDIM + gx;
        voff[it] = row * SEQ + gx;
    }

#pragma unroll
    for (int it = 0; it < 2; ++it) {
        const int i = wave * 2 + it;
        lds_load16(&Kb[0][i * 512], kbase + koff[it]);
        lds_load16(&Vb[0][i * 512], vbase + voff[it]);
    }
    __syncthreads();

    for (int kt = 0; kt < NT; ++kt) {
        const int cur = kt & 1;
        if (kt + 1 < NT) {
            const int nxt = cur ^ 1;
#pragma unroll
            for (int it = 0; it < 2; ++it) {
                const int i = wave * 2 + it;
                lds_load16(&Kb[nxt][i * 512], kbase + (kt + 1) * BC * HDIM + koff[it]);
                lds_load16(&Vb[nxt][i * 512], vbase + (kt + 1) * BC + voff[it]);
            }
        }

        // mask B-fragments for the rowsum MFMA (consumed at the tail)
        s8v mb0 = *(const s8v*)&mrow[kt * BC + quad * 8];
        s8v mb1 = *(const s8v*)&mrow[kt * BC + 32 + quad * 8];

        f4v sacc[4][4];
#pragma unroll
        for (int qf = 0; qf < 4; ++qf)
#pragma unroll
            for (int mf = 0; mf < 4; ++mf)
                sacc[qf][mf] = (f4v){0.f, 0.f, 0.f, 0.f};

        __builtin_amdgcn_s_setprio(1);
#pragma unroll
        for (int mf = 0; mf < 4; ++mf) {
#pragma unroll
            for (int ds = 0; ds < 2; ++ds) {
                s8v kh = *(const s8v*)&Kb[cur][(mf * 16 + l15) * HDIM + (((ds * 4 + quad) ^ sw) * 8)];
#pragma unroll
                for (int qf = 0; qf < 4; ++qf)
                    sacc[qf][mf] = __builtin_amdgcn_mfma_f32_16x16x32_bf16(kh, qh[qf][ds], sacc[qf][mf], 0, 0, 0);
            }
        }
        __builtin_amdgcn_s_setprio(0);

        // softmax + in-register P redistribution (proven pattern)
        s8v pa[4][2];
#pragma unroll
        for (int qf = 0; qf < 4; ++qf) {
            unsigned int wlo[4], whi[4];
#pragma unroll
            for (int mf = 0; mf < 4; ++mf) {
                float e0 = __builtin_amdgcn_exp2f(sacc[qf][mf][0]);
                float e1 = __builtin_amdgcn_exp2f(sacc[qf][mf][1]);
                float e2 = __builtin_amdgcn_exp2f(sacc[qf][mf][2]);
                float e3 = __builtin_amdgcn_exp2f(sacc[qf][mf][3]);
                wlo[mf] = pkbf(e0, e1);
                whi[mf] = pkbf(e2, e3);
            }
#pragma unroll
            for (int ks = 0; ks < 2; ++ks) {
                unsigned int alo = wlo[ks * 2], blo = wlo[ks * 2 + 1];
                unsigned int ahi = whi[ks * 2], bhi = whi[ks * 2 + 1];
                u2v r;
                r = __builtin_amdgcn_permlane32_swap(alo, blo, false, false); alo = r[0]; blo = r[1];
                r = __builtin_amdgcn_permlane32_swap(ahi, bhi, false, false); ahi = r[0]; bhi = r[1];
                r = __builtin_amdgcn_permlane16_swap(alo, blo, false, false); alo = r[0]; blo = r[1];
                r = __builtin_amdgcn_permlane16_swap(ahi, bhi, false, false); ahi = r[0]; bhi = r[1];
                union { unsigned int w[4]; s8v v; } up;
                up.w[0] = alo; up.w[1] = ahi; up.w[2] = blo; up.w[3] = bhi;
                pa[qf][ks] = up.v;
            }
        }

        __builtin_amdgcn_s_setprio(1);
#pragma unroll
        for (int ks = 0; ks < 2; ++ks) {
            const int csw = ((ks * 4 + quad) ^ sw) * 8;
#pragma unroll
            for (int nf = 0; nf < 4; ++nf) {
                s8v vb = *(const s8v*)&Vb[cur][(nf * 16 + l15) * BC + csw];
#pragma unroll
                for (int qf = 0; qf < 4; ++qf)
                    oacc[qf][nf] = __builtin_amdgcn_mfma_f32_16x16x32_bf16(pa[qf][ks], vb, oacc[qf][nf], 0, 0, 0);
            }
            const s8v mb = ks ? mb1 : mb0;
#pragma unroll
            for (int qf = 0; qf < 4; ++qf)
                lacc[qf] = __builtin_amdgcn_mfma_f32_16x16x32_bf16(pa[qf][ks], mb, lacc[qf], 0, 0, 0);
        }
        __builtin_amdgcn_s_setprio(0);
        __syncthreads();
    }

    // epilogue: normalize with lane-local rowsums (no shuffles needed)
#pragma unroll
    for (int qf = 0; qf < 4; ++qf) {
        float lv[4];
#pragma unroll
        for (int r = 0; r < 4; ++r) lv[r] = 1.0f / lacc[qf][r];
#pragma unroll
        for (int nf = 0; nf < 4; ++nf)
#pragma unroll
            for (int r = 0; r < 4; ++r) {
                int q = qbase + qf * 16 + quad * 4 + r;
                int d = nf * 16 + l15;
                out[((size_t)b * SEQ + q) * HID + h * HDIM + d] = oacc[qf][nf][r] * lv[r];
            }
    }
}

extern "C" void kernel_launch(void* const* d_in, const int* in_sizes, int n_in,
                              void* d_out, int out_size, void* d_ws, size_t ws_size,
                              hipStream_t stream) {
    const float* hs   = (const float*)d_in[0];
    const float* mask = (const float*)d_in[1];
    const float* Wq   = (const float*)d_in[2];
    const float* bq   = (const float*)d_in[3];
    const float* Wk   = (const float*)d_in[4];
    const float* bk   = (const float*)d_in[5];
    const float* Wv   = (const float*)d_in[6];
    const float* bv   = (const float*)d_in[7];
    float* out = (float*)d_out;

    const size_t N = (size_t)MROWS * HID;        // 4.19M u16 per array
    unsigned short* Qg  = (unsigned short*)d_ws;
    unsigned short* Khi = Qg + N;
    unsigned short* VTg = Qg + 2 * N;
    unsigned short* Ah  = Qg + 3 * N;
    unsigned short* WTh = Qg + 4 * N;            // 3*HID*HID u16 (stacked QKV)
    unsigned short* maskbf = WTh + (size_t)3 * HID * HID;  // B*S u16

    conv_fused_kernel<<<2048 + 768 + 16, 256, 0, stream>>>(hs, mask, Wq, Wk, Wv, Ah, WTh, maskbf);

    dim3 g1(MROWS / 128, 3 * HID / 128);  // 32 x 24 = 768 blocks, 2/CU
    qkv_mfma_kernel<<<g1, 256, 0, stream>>>(Ah, WTh, bq, bk, bv, mask, Qg, Khi, VTg);

    dim3 g2(BHT, SEQ / 256);              // 32 x 8 = 256 blocks, 1/CU
    attn_mfma_kernel<<<g2, 256, 0, stream>>>(Qg, Khi, VTg, maskbf, out);
}

// Round 8
// 162.816 us; speedup vs baseline: 1.1218x; 1.1218x over previous
//
#include <hip/hip_runtime.h>
#include <hip/hip_bf16.h>
#include <cstddef>
#include <cstdint>

#define HID 1024
#define NHEADS 16
#define HDIM 64
#define BATCH 2
#define SEQ 2048
#define MROWS (BATCH * SEQ)   // 4096
#define BHT (BATCH * NHEADS)  // 32

typedef __attribute__((ext_vector_type(8))) short s8v;   // 8 x bf16 (4 VGPR)
typedef __attribute__((ext_vector_type(4))) float f4v;   // MFMA C/D frag
typedef __attribute__((ext_vector_type(2))) unsigned int u2v;

__device__ __forceinline__ unsigned int pkbf(float a, float b) {
    __hip_bfloat162 h = __float22bfloat162_rn(float2{a, b});  // x -> low 16
    union { __hip_bfloat162 v; unsigned int u; } c; c.v = h; return c.u;
}

__device__ __forceinline__ void lds_load16(void* lds, const void* g) {
    __builtin_amdgcn_global_load_lds(
        (const __attribute__((address_space(1))) void*)g,
        (__attribute__((address_space(3))) void*)lds, 16, 0, 0);
}

// ---------------- Stage 0: fused conversions + bf16 mask --------------------
__global__ __launch_bounds__(256) void conv_fused_kernel(
    const float* __restrict__ hs, const float* __restrict__ mask,
    const float* __restrict__ Wq, const float* __restrict__ Wk,
    const float* __restrict__ Wv,
    unsigned short* __restrict__ Ah, unsigned short* __restrict__ WTh,
    unsigned short* __restrict__ maskbf)
{
    if (blockIdx.x < 2048) {
        const int idx = (blockIdx.x * 256 + threadIdx.x) * 8;
        float4 v0 = *(const float4*)&hs[idx];
        float4 v1 = *(const float4*)&hs[idx + 4];
        union { unsigned int w[4]; } pk;
        pk.w[0] = pkbf(v0.x, v0.y);
        pk.w[1] = pkbf(v0.z, v0.w);
        pk.w[2] = pkbf(v1.x, v1.y);
        pk.w[3] = pkbf(v1.z, v1.w);
        *(uint4*)&Ah[idx] = *(uint4*)&pk;
    } else if (blockIdx.x < 2816) {
        const int bid = blockIdx.x - 2048;
        const int z = bid >> 8;
        const int rem = bid & 255;
        const float* W = (z == 0) ? Wq : (z == 1) ? Wk : Wv;
        unsigned short* th = WTh + (size_t)z * HID * HID;

        __shared__ float tile[64][65];
        const int t = threadIdx.x;
        const int kb = (rem >> 4) * 64, nb = (rem & 15) * 64;
        const int c4 = (t & 15) * 4;
        const int r0 = t >> 4;

#pragma unroll
        for (int i = 0; i < 4; ++i) {
            int r = r0 + i * 16;
            float4 v = *(const float4*)&W[(size_t)(kb + r) * HID + nb + c4];
            tile[r][c4 + 0] = v.x; tile[r][c4 + 1] = v.y;
            tile[r][c4 + 2] = v.z; tile[r][c4 + 3] = v.w;
        }
        __syncthreads();
#pragma unroll
        for (int i = 0; i < 4; ++i) {
            int n = r0 + i * 16;
            union { unsigned int w[2]; unsigned long long q; } pk;
            pk.w[0] = pkbf(tile[c4 + 0][n], tile[c4 + 1][n]);
            pk.w[1] = pkbf(tile[c4 + 2][n], tile[c4 + 3][n]);
            *(unsigned long long*)&th[(size_t)(nb + n) * HID + kb + c4] = pk.q;
        }
    } else {
        // bf16 copy of the {0,1} attention mask (B-fragment for the rowsum MFMA)
        const int idx = (blockIdx.x - 2816) * 256 + threadIdx.x;
        union { unsigned int u; unsigned short s[2]; } cv;
        cv.u = pkbf(mask[idx], 0.f);
        maskbf[idx] = cv.s[0];
    }
}

// ---------------- Stage 1: unified QKV GEMM, 2-phase pipelined --------------
// yb<8: Q (swapped MFMA, scale+bias); yb<16: K; else V (bias, x mask -> VTg).
#define QSCALE 0.18033688011112042f   // 0.125 * log2(e)

__global__ __launch_bounds__(256, 2) void qkv_mfma_kernel(
    const unsigned short* __restrict__ Ah, const unsigned short* __restrict__ WTh,
    const float* __restrict__ bq, const float* __restrict__ bk,
    const float* __restrict__ bv, const float* __restrict__ mask,
    unsigned short* __restrict__ Qg, unsigned short* __restrict__ Khi,
    unsigned short* __restrict__ VTg)
{
    __shared__ unsigned short S[32768];   // 64 KB: 2 bufs x (A 16KB + B 16KB)

    const int t = threadIdx.x;
    const int wave = t >> 6, lane = t & 63, quad = lane >> 4, l15 = lane & 15;
    const int sw = l15 & 7;
    const int wm = wave >> 1, wn = wave & 1;
    const int rowBase = blockIdx.x * 128;
    const int yb = blockIdx.y;             // 0..23
    const int colBase = yb * 128;          // row in stacked [3072][1024] WTh

    const int srow8 = lane >> 3;
    const int sc    = lane & 7;
    size_t goffA[4], goffB[4];
#pragma unroll
    for (int it = 0; it < 4; ++it) {
        const int row = (wave * 4 + it) * 8 + srow8;
        const int gx = (sc ^ (row & 7)) * 8;
        goffA[it] = (size_t)(rowBase + row) * HID + gx;
        goffB[it] = (size_t)(colBase + row) * HID + gx;
    }

    f4v acc[4][4];
#pragma unroll
    for (int mf = 0; mf < 4; ++mf)
#pragma unroll
        for (int nf = 0; nf < 4; ++nf) acc[mf][nf] = (f4v){0.f, 0.f, 0.f, 0.f};

    // prologue: stage K-step 0 into buffer 0
#pragma unroll
    for (int it = 0; it < 4; ++it) {
        lds_load16(&S[(wave * 4 + it) * 512], &Ah[goffA[it]]);
        lds_load16(&S[8192 + (wave * 4 + it) * 512], &WTh[goffB[it]]);
    }
    __syncthreads();

    const bool isQK = (yb < 16);           // block-uniform

    for (int kt = 0; kt < HID / 64; ++kt) {
        const int cur = (kt & 1) << 14;    // 0 / 16384 (u16 elems)
        const int nxt = cur ^ 16384;
        if (kt < HID / 64 - 1) {
            const int k0 = (kt + 1) * 64;
#pragma unroll
            for (int it = 0; it < 4; ++it) {
                lds_load16(&S[nxt + (wave * 4 + it) * 512], &Ah[goffA[it] + k0]);
                lds_load16(&S[nxt + 8192 + (wave * 4 + it) * 512], &WTh[goffB[it] + k0]);
            }
        }
        const unsigned short* AS = &S[cur];
        const unsigned short* BS = &S[cur + 8192];
#pragma unroll
        for (int kk = 0; kk < 2; ++kk) {
            const int csw = ((kk * 4 + quad) ^ sw) * 8;
            s8v af[4], bf[4];
#pragma unroll
            for (int mf = 0; mf < 4; ++mf)
                af[mf] = *(const s8v*)&AS[(wm * 64 + mf * 16 + l15) * 64 + csw];
#pragma unroll
            for (int nf = 0; nf < 4; ++nf)
                bf[nf] = *(const s8v*)&BS[(wn * 64 + nf * 16 + l15) * 64 + csw];
            if (isQK) {
#pragma unroll
                for (int mf = 0; mf < 4; ++mf)
#pragma unroll
                    for (int nf = 0; nf < 4; ++nf)
                        acc[mf][nf] = __builtin_amdgcn_mfma_f32_16x16x32_bf16(bf[nf], af[mf], acc[mf][nf], 0, 0, 0);
            } else {
#pragma unroll
                for (int mf = 0; mf < 4; ++mf)
#pragma unroll
                    for (int nf = 0; nf < 4; ++nf)
                        acc[mf][nf] = __builtin_amdgcn_mfma_f32_16x16x32_bf16(af[mf], bf[nf], acc[mf][nf], 0, 0, 0);
            }
        }
        __syncthreads();
    }

    if (yb < 8) {
        // Q epilogue (swapped layout: acc[mf][nf][r] = C[s][n], n = .. + quad*4 + r)
#pragma unroll
        for (int nf = 0; nf < 4; ++nf) {
            const int n0 = colBase + wn * 64 + nf * 16 + quad * 4;
            const float4 bb = *(const float4*)&bq[n0];
            const int h = n0 >> 6, d0 = n0 & 63;
#pragma unroll
            for (int mf = 0; mf < 4; ++mf) {
                const int rw = rowBase + wm * 64 + mf * 16 + l15;
                const int b = rw >> 11;
                const int ss = rw & (SEQ - 1);
                union { unsigned int w[2]; unsigned long long q; } pk;
                pk.w[0] = pkbf((acc[mf][nf][0] + bb.x) * QSCALE, (acc[mf][nf][1] + bb.y) * QSCALE);
                pk.w[1] = pkbf((acc[mf][nf][2] + bb.z) * QSCALE, (acc[mf][nf][3] + bb.w) * QSCALE);
                *(unsigned long long*)&Qg[((size_t)(b * NHEADS + h) * SEQ + ss) * HDIM + d0] = pk.q;
            }
        }
    } else if (yb < 16) {
        // K epilogue
#pragma unroll
        for (int nf = 0; nf < 4; ++nf) {
            const int nk = colBase - 1024 + wn * 64 + nf * 16 + quad * 4;
            const float4 bb = *(const float4*)&bk[nk];
            const int h = nk >> 6, d0 = nk & 63;
#pragma unroll
            for (int mf = 0; mf < 4; ++mf) {
                const int rw = rowBase + wm * 64 + mf * 16 + l15;
                const int b = rw >> 11;
                const int ss = rw & (SEQ - 1);
                union { unsigned int w[2]; unsigned long long q; } pk;
                pk.w[0] = pkbf(acc[mf][nf][0] + bb.x, acc[mf][nf][1] + bb.y);
                pk.w[1] = pkbf(acc[mf][nf][2] + bb.z, acc[mf][nf][3] + bb.w);
                *(unsigned long long*)&Khi[((size_t)(b * NHEADS + h) * SEQ + ss) * HDIM + d0] = pk.q;
            }
        }
    } else {
        // V epilogue (natural layout), pre-multiplied by the attention mask:
        // o = sum_k p_k * (m_k V_k) makes the QK-side mask add unnecessary.
#pragma unroll
        for (int nf = 0; nf < 4; ++nf) {
            const int nv = colBase - 2048 + wn * 64 + nf * 16 + l15;
            const float bb = bv[nv];
            const int h = nv >> 6, d = nv & 63;
#pragma unroll
            for (int mf = 0; mf < 4; ++mf) {
                const int rw0 = rowBase + wm * 64 + mf * 16 + quad * 4;
                const int b = rw0 >> 11;
                const int s0 = rw0 & (SEQ - 1);
                const float4 mv = *(const float4*)&mask[b * SEQ + s0];
                union { unsigned int w[2]; unsigned long long q; } pk;
                pk.w[0] = pkbf((acc[mf][nf][0] + bb) * mv.x, (acc[mf][nf][1] + bb) * mv.y);
                pk.w[1] = pkbf((acc[mf][nf][2] + bb) * mv.z, (acc[mf][nf][3] + bb) * mv.w);
                *(unsigned long long*)&VTg[((size_t)(b * NHEADS + h) * HDIM + d) * SEQ + s0] = pk.q;
            }
        }
    }
}

// ---------------- Stage 2: flash attention (R6 geometry + mask at tail) -----
// qf=2, 4 waves, grid 32x16 (2 blocks/CU). sacc zero-init (no loads at the
// head of the chain); mask enters at the tail: V pre-masked in qkv, rowsum l
// via bf16-mask B-fragment MFMA. Lane-local normalization (no shuffles).
#define BC 64
#define NT (SEQ / BC)   // 32

__global__ __launch_bounds__(256, 4) void attn_mfma_kernel(
    const unsigned short* __restrict__ Qg, const unsigned short* __restrict__ Khi,
    const unsigned short* __restrict__ VTg,
    const unsigned short* __restrict__ maskbf, float* __restrict__ out)
{
    __shared__ unsigned short Kb[2][BC * HDIM];    // 2 x 8 KB, swizzled
    __shared__ unsigned short Vb[2][BC * HDIM];    // 2 x 8 KB, swizzled (V^T)

    const int t = threadIdx.x;
    const int wave = t >> 6, lane = t & 63, quad = lane >> 4, l15 = lane & 15;
    const int sw = l15 & 7;
    const int bh = blockIdx.x, b = bh >> 4, h = bh & (NHEADS - 1);
    const int qbase = blockIdx.y * 128 + wave * 32;

    const size_t hb = (size_t)bh * SEQ * HDIM;
    const unsigned short* kbase = Khi + hb;
    const unsigned short* vbase = VTg + hb;
    const unsigned short* mrow = maskbf + b * SEQ;

    s8v qh[2][2];
#pragma unroll
    for (int qf = 0; qf < 2; ++qf)
#pragma unroll
        for (int ds = 0; ds < 2; ++ds) {
            size_t off = hb + (size_t)(qbase + qf * 16 + l15) * HDIM + ds * 32 + quad * 8;
            qh[qf][ds] = *(const s8v*)&Qg[off];
        }

    f4v oacc[2][4], lacc[2];
#pragma unroll
    for (int qf = 0; qf < 2; ++qf) {
#pragma unroll
        for (int nf = 0; nf < 4; ++nf) oacc[qf][nf] = (f4v){0.f, 0.f, 0.f, 0.f};
        lacc[qf] = (f4v){0.f, 0.f, 0.f, 0.f};
    }

    // staging: 4 waves x 2 slices cover each 64x64 tile
    const int srow8 = lane >> 3;
    const int sc    = lane & 7;
    int koff[2], voff[2];
#pragma unroll
    for (int it = 0; it < 2; ++it) {
        const int row = (wave * 2 + it) * 8 + srow8;
        const int gx = (sc ^ (row & 7)) * 8;
        koff[it] = row * HDIM + gx;
        voff[it] = row * SEQ + gx;
    }

#pragma unroll
    for (int it = 0; it < 2; ++it) {
        const int i = wave * 2 + it;
        lds_load16(&Kb[0][i * 512], kbase + koff[it]);
        lds_load16(&Vb[0][i * 512], vbase + voff[it]);
    }
    __syncthreads();

    for (int kt = 0; kt < NT; ++kt) {
        const int cur = kt & 1;
        if (kt + 1 < NT) {
            const int nxt = cur ^ 1;
#pragma unroll
            for (int it = 0; it < 2; ++it) {
                const int i = wave * 2 + it;
                lds_load16(&Kb[nxt][i * 512], kbase + (kt + 1) * BC * HDIM + koff[it]);
                lds_load16(&Vb[nxt][i * 512], vbase + (kt + 1) * BC + voff[it]);
            }
        }

        // mask B-fragments for the rowsum MFMA (tail; overlap the QK phase)
        s8v mb0 = *(const s8v*)&mrow[kt * BC + quad * 8];
        s8v mb1 = *(const s8v*)&mrow[kt * BC + 32 + quad * 8];

        f4v sacc[2][4];
#pragma unroll
        for (int qf = 0; qf < 2; ++qf)
#pragma unroll
            for (int mf = 0; mf < 4; ++mf)
                sacc[qf][mf] = (f4v){0.f, 0.f, 0.f, 0.f};

        __builtin_amdgcn_s_setprio(1);
#pragma unroll
        for (int mf = 0; mf < 4; ++mf) {
#pragma unroll
            for (int ds = 0; ds < 2; ++ds) {
                s8v kh = *(const s8v*)&Kb[cur][(mf * 16 + l15) * HDIM + (((ds * 4 + quad) ^ sw) * 8)];
#pragma unroll
                for (int qf = 0; qf < 2; ++qf)
                    sacc[qf][mf] = __builtin_amdgcn_mfma_f32_16x16x32_bf16(kh, qh[qf][ds], sacc[qf][mf], 0, 0, 0);
            }
        }
        __builtin_amdgcn_s_setprio(0);

        // softmax + in-register P redistribution (proven pattern)
        s8v pa[2][2];
#pragma unroll
        for (int qf = 0; qf < 2; ++qf) {
            unsigned int wlo[4], whi[4];
#pragma unroll
            for (int mf = 0; mf < 4; ++mf) {
                float e0 = __builtin_amdgcn_exp2f(sacc[qf][mf][0]);
                float e1 = __builtin_amdgcn_exp2f(sacc[qf][mf][1]);
                float e2 = __builtin_amdgcn_exp2f(sacc[qf][mf][2]);
                float e3 = __builtin_amdgcn_exp2f(sacc[qf][mf][3]);
                wlo[mf] = pkbf(e0, e1);
                whi[mf] = pkbf(e2, e3);
            }
#pragma unroll
            for (int ks = 0; ks < 2; ++ks) {
                unsigned int alo = wlo[ks * 2], blo = wlo[ks * 2 + 1];
                unsigned int ahi = whi[ks * 2], bhi = whi[ks * 2 + 1];
                u2v r;
                r = __builtin_amdgcn_permlane32_swap(alo, blo, false, false); alo = r[0]; blo = r[1];
                r = __builtin_amdgcn_permlane32_swap(ahi, bhi, false, false); ahi = r[0]; bhi = r[1];
                r = __builtin_amdgcn_permlane16_swap(alo, blo, false, false); alo = r[0]; blo = r[1];
                r = __builtin_amdgcn_permlane16_swap(ahi, bhi, false, false); ahi = r[0]; bhi = r[1];
                union { unsigned int w[4]; s8v v; } up;
                up.w[0] = alo; up.w[1] = ahi; up.w[2] = blo; up.w[3] = bhi;
                pa[qf][ks] = up.v;
            }
        }

        __builtin_amdgcn_s_setprio(1);
#pragma unroll
        for (int ks = 0; ks < 2; ++ks) {
            const int csw = ((ks * 4 + quad) ^ sw) * 8;
#pragma unroll
            for (int nf = 0; nf < 4; ++nf) {
                s8v vb = *(const s8v*)&Vb[cur][(nf * 16 + l15) * BC + csw];
                oacc[0][nf] = __builtin_amdgcn_mfma_f32_16x16x32_bf16(pa[0][ks], vb, oacc[0][nf], 0, 0, 0);
                oacc[1][nf] = __builtin_amdgcn_mfma_f32_16x16x32_bf16(pa[1][ks], vb, oacc[1][nf], 0, 0, 0);
            }
            // rowsum l on the matrix pipe against the bf16 mask fragment
            const s8v mb = ks ? mb1 : mb0;
            lacc[0] = __builtin_amdgcn_mfma_f32_16x16x32_bf16(pa[0][ks], mb, lacc[0], 0, 0, 0);
            lacc[1] = __builtin_amdgcn_mfma_f32_16x16x32_bf16(pa[1][ks], mb, lacc[1], 0, 0, 0);
        }
        __builtin_amdgcn_s_setprio(0);
        __syncthreads();
    }

    // epilogue: normalize with lane-local rowsums (no shuffles needed)
#pragma unroll
    for (int qf = 0; qf < 2; ++qf) {
        float lv[4];
#pragma unroll
        for (int r = 0; r < 4; ++r) lv[r] = 1.0f / lacc[qf][r];
#pragma unroll
        for (int nf = 0; nf < 4; ++nf)
#pragma unroll
            for (int r = 0; r < 4; ++r) {
                int q = qbase + qf * 16 + quad * 4 + r;
                int d = nf * 16 + l15;
                out[((size_t)b * SEQ + q) * HID + h * HDIM + d] = oacc[qf][nf][r] * lv[r];
            }
    }
}

extern "C" void kernel_launch(void* const* d_in, const int* in_sizes, int n_in,
                              void* d_out, int out_size, void* d_ws, size_t ws_size,
                              hipStream_t stream) {
    const float* hs   = (const float*)d_in[0];
    const float* mask = (const float*)d_in[1];
    const float* Wq   = (const float*)d_in[2];
    const float* bq   = (const float*)d_in[3];
    const float* Wk   = (const float*)d_in[4];
    const float* bk   = (const float*)d_in[5];
    const float* Wv   = (const float*)d_in[6];
    const float* bv   = (const float*)d_in[7];
    float* out = (float*)d_out;

    const size_t N = (size_t)MROWS * HID;        // 4.19M u16 per array
    unsigned short* Qg  = (unsigned short*)d_ws;
    unsigned short* Khi = Qg + N;
    unsigned short* VTg = Qg + 2 * N;
    unsigned short* Ah  = Qg + 3 * N;
    unsigned short* WTh = Qg + 4 * N;            // 3*HID*HID u16 (stacked QKV)
    unsigned short* maskbf = WTh + (size_t)3 * HID * HID;  // B*S u16

    conv_fused_kernel<<<2048 + 768 + 16, 256, 0, stream>>>(hs, mask, Wq, Wk, Wv, Ah, WTh, maskbf);

    dim3 g1(MROWS / 128, 3 * HID / 128);  // 32 x 24 = 768 blocks, 2/CU
    qkv_mfma_kernel<<<g1, 256, 0, stream>>>(Ah, WTh, bq, bk, bv, mask, Qg, Khi, VTg);

    dim3 g2(BHT, SEQ / 128);              // 32 x 16 = 512 blocks, 2/CU
    attn_mfma_kernel<<<g2, 256, 0, stream>>>(Qg, Khi, VTg, maskbf, out);
}